// Round 4
// baseline (163.401 us; speedup 1.0000x reference)
//
#include <hip/hip_runtime.h>

#define B 8
#define P 2048
#define C 1024
#define NCHUNK 32
#define FEAT4 (B*P*C/4)   // 4194304 float4s of features
#define CEN4  (B*P*3/4)   // 12288 float4s of centers (and of cls_preds)

typedef unsigned long long u64;
typedef unsigned int u32;

// ---------------------------------------------------------------------------
// K1: full-GPU rank sort (R7, unchanged). Keys unique => rank is a bijection.
// ---------------------------------------------------------------------------
__global__ __launch_bounds__(512) void rank_kernel(
    const float* __restrict__ centers,
    const float* __restrict__ cls_preds,
    float4* __restrict__ scent,
    int* __restrict__ sidx)
{
    __shared__ u64 s_keys[P];       // 16 KB
    __shared__ u32 s_cnt[64][9];    // padded reduce buffer
    const int b = blockIdx.x >> 5, gi = blockIdx.x & 31;
    const int tid = threadIdx.x, wv = tid >> 6, lane = tid & 63;
    const float* clsb = cls_preds + (size_t)b * P * 3;
    const float* cenb = centers + (size_t)b * P * 3;

    for (int e = tid; e < P; e += 512) {
        float s0 = clsb[e*3], s1 = clsb[e*3+1], s2 = clsb[e*3+2];
        float sc = s0; int lb = 0;
        if (s1 > sc) { sc = s1; lb = 1; }
        if (s2 > sc) { sc = s2; lb = 2; }
        u32 ub = __float_as_uint(sc);
        u32 ord = (ub & 0x80000000u) ? ~ub : (ub | 0x80000000u);
        s_keys[e] = ((u64)(~ord) << 32) | (u32)((e << 2) | lb);
    }
    __syncthreads();

    const u64 myk = s_keys[(gi << 6) + lane];
    u32 c = 0;
    const int sbase = wv << 8;
    #pragma unroll 8
    for (int u = 0; u < 256; ++u)            // wave-uniform -> broadcast, free
        c += (s_keys[sbase + u] < myk) ? 1u : 0u;
    s_cnt[lane][wv] = c;
    __syncthreads();

    if (wv == 0) {
        u32 rank = 0;
        #pragma unroll
        for (int s = 0; s < 8; ++s) rank += s_cnt[lane][s];
        u32 lo = (u32)myk;
        int orig = (int)(lo >> 2);
        float4 cc;
        cc.x = cenb[orig*3]; cc.y = cenb[orig*3+1]; cc.z = cenb[orig*3+2];
        cc.w = __int_as_float((int)(lo & 3));
        scent[(size_t)b * P + rank] = cc;
        sidx[(size_t)b * P + rank] = (int)lo;
    }
}

// ---------------------------------------------------------------------------
// K2 (R15): FULL-SQUARE suppression matrix, u64 chunk-row-pairs.
// matI[b][g][j] = 64-bit word: bit u = mutual suppression between point
// (64g+u) and point j (both in sorted order). No triangle trim -- the
// single-wave scan consumes rows of chunk g at ALL columns (forward supp
// update), and full coverage kills every poison/replay hazard.
// Work per thread: 4 u64-iterations x 64 inner (vs avg ~4.9 trimmed u32
// before -- slightly cheaper, and stores are 8B coalesced).
// ---------------------------------------------------------------------------
__global__ __launch_bounds__(512) void matrix_kernel(
    const float4* __restrict__ scent,
    const float* __restrict__ class_radius,
    u64* __restrict__ matI)
{
    __shared__ float4 s_cent[P];   // 32 KB
    const int b = blockIdx.x >> 5, gi = blockIdx.x & 31;
    const int tid = threadIdx.x, wv = tid >> 6, lane = tid & 63;

    const float4 cj = scent[(size_t)b * P + (gi << 6) + lane];  // coalesced
    const int labj = __float_as_int(cj.w);
    const float r = class_radius[labj];
    const float r2 = r * r;

    for (int i = tid; i < P; i += 512) s_cent[i] = scent[(size_t)b * P + i];
    __syncthreads();

    for (int p = wv; p < 32; p += 8) {
        u32 lo = 0, hi = 0;
        #pragma unroll
        for (int u = 0; u < 32; ++u) {
            float4 ci = s_cent[(p << 6) + u];         // uniform -> broadcast
            float dx = cj.x - ci.x, dy = cj.y - ci.y, dz = cj.z - ci.z;
            bool sup = (__float_as_int(ci.w) == labj)
                       && (dx*dx + dy*dy + dz*dz < r2);
            lo |= ((u32)sup) << u;
        }
        #pragma unroll
        for (int u = 0; u < 32; ++u) {
            float4 ci = s_cent[(p << 6) + 32 + u];
            float dx = cj.x - ci.x, dy = cj.y - ci.y, dz = cj.z - ci.z;
            bool sup = (__float_as_int(ci.w) == labj)
                       && (dx*dx + dy*dy + dz*dz < r2);
            hi |= ((u32)sup) << u;
        }
        matI[((size_t)b * 32 + p) * P + (gi << 6) + lane]
            = (u64)lo | ((u64)hi << 32);              // 8B coalesced
    }
}

// ---------------------------------------------------------------------------
// K3 (R15): SINGLE-WAVE greedy resolution. 8 blocks x 64 threads.
//
// R14 lesson: barrier count wasn't the cost -- the cross-wave machinery was
// (s_removed LDS round-trips, atomicOr, 9-wave convergence, lockstep).
// One wave holds the whole state:
//   supp     (u32/lane): bit h = my point of chunk h already suppressed
//   keepbits (u32/lane): bit g = my point of chunk g kept
// Per chunk g: alive = ~ballot(supp bit g); peel with diag row; then
// forward-update ALL future chunks: supp |= ((bank[h] & keepm)!=0) << h,
// masked to h > g. bank[h] = matI[b][g][64h+lane] -- prefetched one chunk
// pair ahead into 2 static-indexed register banks (ping-pong, ~960 cy lead).
// No barriers, no LDS, no atomics; compiler-placed vmcnt waits at first use.
// ---------------------------------------------------------------------------
#define PROCESS(BK, DG, g)                                                   \
  {                                                                          \
    u64 alive = ~__ballot(((supp >> (g)) & 1u) != 0u);                       \
    const u64 row = (DG);                                                    \
    u64 keepm = 0;                                                           \
    while (alive) {                   /* rounds = greedy chain depth */      \
      bool okk = ((alive >> lane) & 1ull) && ((row & alive & below) == 0ull);\
      u64 newk = __ballot(okk);                                              \
      keepm |= newk;                                                         \
      bool dead = (row & newk) != 0ull;                                      \
      u64 deadm = __ballot(dead);                                            \
      alive &= ~(newk | deadm);                                              \
    }                                                                        \
    keepbits |= ((u32)((keepm >> lane) & 1ull)) << (g);                      \
    u32 nb = 0;                                                              \
    _Pragma("unroll")                                                        \
    for (int h = 0; h < 32; ++h)                                             \
      nb |= ((BK[h] & keepm) != 0ull ? 1u : 0u) << h;                        \
    supp |= nb & (u32)~((2ull << (g)) - 1ull);  /* only future chunks */     \
  }

#define RELOAD(BK, DG, g)                                                    \
  {                                                                          \
    const u64* pp = mbI + (size_t)(g) * P + lane;                            \
    _Pragma("unroll")                                                        \
    for (int h = 0; h < 32; ++h) BK[h] = pp[h * 64];                         \
    (DG) = pp[(g) * 64];                                                     \
  }

__global__ __launch_bounds__(64, 1) void scan_kernel(
    const u64* __restrict__ matI,
    const int* __restrict__ sidx,
    float* __restrict__ out_keep)
{
    const int b = blockIdx.x;
    const int lane = threadIdx.x;             // one wave per block
    const u64* mbI = matI + (size_t)b * 32 * P;
    const u64 below = (1ull << lane) - 1ull;

    u64 bank0[32], bank1[32];                 // static-indexed -> registers
    u64 d0, d1;
    u32 supp = 0, keepbits = 0;

    RELOAD(bank0, d0, 0);
    RELOAD(bank1, d1, 1);

    for (int t = 0; t < NCHUNK / 2; ++t) {
        const int g = 2 * t;
        PROCESS(bank0, d0, g);
        if (t < NCHUNK / 2 - 1) RELOAD(bank0, d0, g + 2);
        PROCESS(bank1, d1, g + 1);
        if (t < NCHUNK / 2 - 1) RELOAD(bank1, d1, g + 3);
    }

    // tail: load sorted->orig map, scatter keep bits
    const int* sp = sidx + (size_t)b * P;
    int sv[32];
    #pragma unroll
    for (int h = 0; h < 32; ++h) sv[h] = sp[h * 64 + lane];
    float* okp = out_keep + (size_t)b * P;
    #pragma unroll
    for (int h = 0; h < 32; ++h)
        okp[sv[h] >> 2] = ((keepbits >> h) & 1u) ? 1.0f : 0.0f;
}

// ---------------------------------------------------------------------------
// K4: streaming mask (unchanged). Suppressed feature rows are store-only.
// ---------------------------------------------------------------------------
__global__ __launch_bounds__(256) void mask_kernel(
    const float* __restrict__ centers,
    const float* __restrict__ features,
    const float* __restrict__ cls_preds,
    const float* __restrict__ keep,
    float* __restrict__ out_centers,
    float* __restrict__ out_feat,
    float* __restrict__ out_cls)
{
    const int idx = blockIdx.x * 256 + threadIdx.x;
    if (idx < FEAT4) {
        const int row = idx >> 8;                    // C/4 = 256 f4 per row
        const float m = keep[row];                   // block-uniform
        if (m != 0.0f) {
            float4 v = ((const float4*)features)[idx];
            v.x *= m; v.y *= m; v.z *= m; v.w *= m;
            ((float4*)out_feat)[idx] = v;
        } else {
            float4 z; z.x = 0.f; z.y = 0.f; z.z = 0.f; z.w = 0.f;
            ((float4*)out_feat)[idx] = z;            // store-only: no fetch
        }
    } else if (idx < FEAT4 + CEN4) {
        const int q = idx - FEAT4;
        float4 v = ((const float4*)centers)[q];
        const int e = q * 4;
        v.x *= keep[(e    ) / 3]; v.y *= keep[(e + 1) / 3];
        v.z *= keep[(e + 2) / 3]; v.w *= keep[(e + 3) / 3];
        ((float4*)out_centers)[q] = v;
    } else if (idx < FEAT4 + 2 * CEN4) {
        const int q = idx - FEAT4 - CEN4;
        float4 v = ((const float4*)cls_preds)[q];
        const int e = q * 4;
        v.x *= keep[(e    ) / 3]; v.y *= keep[(e + 1) / 3];
        v.z *= keep[(e + 2) / 3]; v.w *= keep[(e + 3) / 3];
        ((float4*)out_cls)[q] = v;
    }
}

extern "C" void kernel_launch(void* const* d_in, const int* in_sizes, int n_in,
                              void* d_out, int out_size, void* d_ws, size_t ws_size,
                              hipStream_t stream) {
    const float* centers      = (const float*)d_in[0];
    const float* features     = (const float*)d_in[1];
    const float* cls_preds    = (const float*)d_in[2];
    const float* class_radius = (const float*)d_in[3];

    float* out = (float*)d_out;
    float* out_centers = out;                                   // B*P*3
    float* out_feat    = out + (size_t)B * P * 3;               // B*P*C
    float* out_cls     = out_feat + (size_t)B * P * C;          // B*P*K
    float* out_keep    = out_cls + (size_t)B * P * 3;           // B*P

    // scratch inside out_feat (64 MB), fully rewritten by mask_kernel:
    //   matI  : B*32*2048 u64 = 4 MB (out_feat byte offset 0)
    //   scent : 16,384 float4
    //   sidx  : 16,384 int
    u64*    matI  = (u64*)out_feat;
    float4* scent = (float4*)(out_feat + 1048576);
    int*    sidx  = (int*)(out_feat + 1048576 + 65536);

    hipLaunchKernelGGL(rank_kernel, dim3(B * 32), dim3(512), 0, stream,
                       centers, cls_preds, scent, sidx);
    hipLaunchKernelGGL(matrix_kernel, dim3(B * 32), dim3(512), 0, stream,
                       scent, class_radius, matI);
    hipLaunchKernelGGL(scan_kernel, dim3(B), dim3(64), 0, stream,
                       matI, sidx, out_keep);
    hipLaunchKernelGGL(mask_kernel, dim3((FEAT4 + 2 * CEN4 + 255) / 256), dim3(256),
                       0, stream,
                       centers, features, cls_preds, out_keep,
                       out_centers, out_feat, out_cls);
}